// Round 8
// baseline (246.052 us; speedup 1.0000x reference)
//
#include <hip/hip_runtime.h>
#include <hip/hip_bf16.h>

typedef __hip_bfloat16 bf16;
typedef short short8 __attribute__((ext_vector_type(8)));
typedef short bs4 __attribute__((ext_vector_type(4)));   // NOT short4 (HIP owns that name)
typedef float f32x4 __attribute__((ext_vector_type(4)));

#define MFMA_BF16(a, b, c) __builtin_amdgcn_mfma_f32_16x16x32_bf16(a, b, c, 0, 0, 0)
#define MFMA16_BF16(a, b, c) __builtin_amdgcn_mfma_f32_16x16x16bf16_1k(a, b, c, 0, 0, 0)

// log2(e)/sqrt(1024): folded into Q-projection so attn exp is raw v_exp_f32
#define QSCALE 0.045084439f

// async global->LDS 16B: LDS dest is wave-uniform base; HW scatters lane i to +16B*i
__device__ __forceinline__ void async_copy16(const bf16* g, bf16* l) {
    __builtin_amdgcn_global_load_lds(
        (const __attribute__((address_space(1))) unsigned int*)(const void*)g,
        (__attribute__((address_space(3))) unsigned int*)(void*)l, 16, 0, 0);
}

// ---------------------------------------------------------------------------
// f32 -> bf16 pre-convert: q,k,v (4M elems each), Wq,Wk,Wv,Wo (1M each).
// ---------------------------------------------------------------------------
__global__ __launch_bounds__(256) void convert_all(
    const float* __restrict__ q, const float* __restrict__ k, const float* __restrict__ v,
    const float* __restrict__ wq, const float* __restrict__ wk,
    const float* __restrict__ wv, const float* __restrict__ wo,
    bf16* __restrict__ qb, bf16* __restrict__ kb, bf16* __restrict__ vb,
    bf16* __restrict__ wqb, bf16* __restrict__ wkb, bf16* __restrict__ wvb,
    bf16* __restrict__ wob)
{
    int blk = blockIdx.x;
    const float* s; bf16* d; int rel;
    if      (blk < 1024) { s = q;  d = qb;  rel = blk; }
    else if (blk < 2048) { s = k;  d = kb;  rel = blk - 1024; }
    else if (blk < 3072) { s = v;  d = vb;  rel = blk - 2048; }
    else if (blk < 3328) { s = wq; d = wqb; rel = blk - 3072; }
    else if (blk < 3584) { s = wk; d = wkb; rel = blk - 3328; }
    else if (blk < 3840) { s = wv; d = wvb; rel = blk - 3584; }
    else                 { s = wo; d = wob; rel = blk - 3840; }
    size_t base = (size_t)rel * 1024 + threadIdx.x;  // float4 index
#pragma unroll
    for (int i = 0; i < 4; i++) {
        float4 f = ((const float4*)s)[base + i * 256];
        union { bf16 h[4]; uint2 u; } pk;
        pk.h[0] = (bf16)f.x; pk.h[1] = (bf16)f.y;
        pk.h[2] = (bf16)f.z; pk.h[3] = (bf16)f.w;
        ((uint2*)d)[base + i * 256] = pk.u;
    }
}

// ---------------------------------------------------------------------------
// Fused QKV projection: grid.x = 24 (8 n-blocks x 3 outputs), grid.y = 32.
// 128x128 tile, BK=64, global_load_lds staging, XOR chunk swizzle.
// sel 0: Q (scaled by QSCALE); sel 1: K; sel 2: V transposed [b][h][64][2048].
// ---------------------------------------------------------------------------
__global__ __launch_bounds__(256) void gemm_qkv(
    const bf16* __restrict__ qb, const bf16* __restrict__ kb, const bf16* __restrict__ vb,
    const bf16* __restrict__ wqb, const bf16* __restrict__ wkb, const bf16* __restrict__ wvb,
    const float* __restrict__ bq, const float* __restrict__ bk, const float* __restrict__ bv,
    bf16* __restrict__ Qp, bf16* __restrict__ Kp, bf16* __restrict__ Vt)
{
    __shared__ bf16 Al[128 * 64];   // 16 KB
    __shared__ bf16 Bl[128 * 64];   // 16 KB

    const int sel = blockIdx.x >> 3;
    const bf16* A; const bf16* W; const float* bias;
    if      (sel == 0) { A = qb; W = wqb; bias = bq; }
    else if (sel == 1) { A = kb; W = wkb; bias = bk; }
    else               { A = vb; W = wvb; bias = bv; }

    const int K = 1024, N = 1024;
    const int t = threadIdx.x;
    const int lane = t & 63, wave = t >> 6;
    const int ln = lane & 15, quad = lane >> 4;
    const int wm = wave >> 1, wn = wave & 1;
    const int m0 = blockIdx.y * 128, n0 = (blockIdx.x & 7) * 128;

    f32x4 acc[4][4];
#pragma unroll
    for (int i = 0; i < 4; i++)
#pragma unroll
        for (int j = 0; j < 4; j++) acc[i][j] = (f32x4){0.f, 0.f, 0.f, 0.f};

    const int lk = ln & 7;
    const int srow = t >> 3, sidx0 = t & 7;

    for (int k0 = 0; k0 < K; k0 += 64) {
        const bf16* Ab = A + (size_t)m0 * K + k0;
        const bf16* Wb = W + (size_t)n0 * K + k0;
#pragma unroll
        for (int p = 0; p < 4; p++) {
            int row = p * 32 + srow, idx = sidx0 ^ (row & 7);
            async_copy16(Ab + (size_t)row * K + idx * 8, &Al[(p * 256 + wave * 64) * 8]);
        }
#pragma unroll
        for (int p = 0; p < 4; p++) {
            int row = p * 32 + srow, idx = sidx0 ^ (row & 7);
            async_copy16(Wb + (size_t)row * K + idx * 8, &Bl[(p * 256 + wave * 64) * 8]);
        }
        __syncthreads();

#pragma unroll
        for (int kk = 0; kk < 2; kk++) {
            short8 af[4], bfr[4];
#pragma unroll
            for (int i = 0; i < 4; i++) {
                int r = wm * 64 + i * 16 + ln;
                af[i] = *(const short8*)&Al[r * 64 + (((kk << 2) | quad) ^ lk) * 8];
            }
#pragma unroll
            for (int j = 0; j < 4; j++) {
                int r = wn * 64 + j * 16 + ln;
                bfr[j] = *(const short8*)&Bl[r * 64 + (((kk << 2) | quad) ^ lk) * 8];
            }
#pragma unroll
            for (int i = 0; i < 4; i++)
#pragma unroll
                for (int j = 0; j < 4; j++)
                    acc[i][j] = MFMA_BF16(af[i], bfr[j], acc[i][j]);
        }
        __syncthreads();
    }

    // epilogue: col(n) = ln, row(m) = quad*4 + r
#pragma unroll
    for (int j = 0; j < 4; j++) {
        int c = n0 + wn * 64 + j * 16 + ln;
        float bv2 = bias[c];
        if (sel == 2) {
            int h = c >> 6, dd = c & 63;
#pragma unroll
            for (int i = 0; i < 4; i++) {
                int m = m0 + wm * 64 + i * 16 + quad * 4;
                int bb = m >> 11, s = m & 2047;
                union { bf16 h4[4]; uint2 u; } pk;
#pragma unroll
                for (int r = 0; r < 4; r++) pk.h4[r] = (bf16)(acc[i][j][r] + bv2);
                *(uint2*)&Vt[(((size_t)(bb * 16 + h)) * 64 + dd) * 2048 + s] = pk.u;
            }
        } else {
            bf16* out = (sel == 0) ? Qp : Kp;
            float scl = (sel == 0) ? QSCALE : 1.0f;
#pragma unroll
            for (int i = 0; i < 4; i++) {
                int rb = m0 + wm * 64 + i * 16 + quad * 4;
#pragma unroll
                for (int r = 0; r < 4; r++)
                    out[(size_t)(rb + r) * N + c] = (bf16)((acc[i][j][r] + bv2) * scl);
            }
        }
    }
}

// ---------------------------------------------------------------------------
// Final GEMM: out[M][N] = AO * Wo^T + bo, f32 output. 128(M)x64(N) tile, BK=64.
// ---------------------------------------------------------------------------
__global__ __launch_bounds__(256) void gemm_fin(
    const bf16* __restrict__ A, const bf16* __restrict__ W,
    const float* __restrict__ bias, float* __restrict__ C)
{
    __shared__ bf16 Al[128 * 64];   // 16 KB
    __shared__ bf16 Bl[64 * 64];    // 8 KB

    const int K = 1024, N = 1024;
    const int t = threadIdx.x;
    const int lane = t & 63, wave = t >> 6;
    const int ln = lane & 15, quad = lane >> 4;
    const int wm = wave >> 1, wn = wave & 1;
    const int m0 = blockIdx.y * 128, n0 = blockIdx.x * 64;

    f32x4 acc[4][2];
#pragma unroll
    for (int i = 0; i < 4; i++)
#pragma unroll
        for (int j = 0; j < 2; j++) acc[i][j] = (f32x4){0.f, 0.f, 0.f, 0.f};

    const int lk = ln & 7;
    const int srow = t >> 3, sidx0 = t & 7;

    for (int k0 = 0; k0 < K; k0 += 64) {
        const bf16* Ab = A + (size_t)m0 * K + k0;
        const bf16* Wb = W + (size_t)n0 * K + k0;
#pragma unroll
        for (int p = 0; p < 4; p++) {
            int row = p * 32 + srow, idx = sidx0 ^ (row & 7);
            async_copy16(Ab + (size_t)row * K + idx * 8, &Al[(p * 256 + wave * 64) * 8]);
        }
#pragma unroll
        for (int p = 0; p < 2; p++) {
            int row = p * 32 + srow, idx = sidx0 ^ (row & 7);
            async_copy16(Wb + (size_t)row * K + idx * 8, &Bl[(p * 256 + wave * 64) * 8]);
        }
        __syncthreads();

#pragma unroll
        for (int kk = 0; kk < 2; kk++) {
            short8 af[4], bfr[2];
#pragma unroll
            for (int i = 0; i < 4; i++) {
                int r = wm * 64 + i * 16 + ln;
                af[i] = *(const short8*)&Al[r * 64 + (((kk << 2) | quad) ^ lk) * 8];
            }
#pragma unroll
            for (int j = 0; j < 2; j++) {
                int r = wn * 32 + j * 16 + ln;
                bfr[j] = *(const short8*)&Bl[r * 64 + (((kk << 2) | quad) ^ lk) * 8];
            }
#pragma unroll
            for (int i = 0; i < 4; i++)
#pragma unroll
                for (int j = 0; j < 2; j++)
                    acc[i][j] = MFMA_BF16(af[i], bfr[j], acc[i][j]);
        }
        __syncthreads();
    }

#pragma unroll
    for (int j = 0; j < 2; j++) {
        int c = n0 + wn * 32 + j * 16 + ln;
        float bv2 = bias[c];
#pragma unroll
        for (int i = 0; i < 4; i++) {
            int rb = m0 + wm * 64 + i * 16 + quad * 4;
#pragma unroll
            for (int r = 0; r < 4; r++)
                C[(size_t)(rb + r) * N + c] = acc[i][j][r] + bv2;
        }
    }
}

// ---------------------------------------------------------------------------
// Flash attention, transposed-score formulation, 64-query blocks (4 blocks/CU
// for TLP: the QK->exp2->pack->PV chain is serially dependent, so we hide it
// with resident waves, not ILP). Each wave owns 16 queries.
//   S^T = K Q^T (A=K-frag, B=Q-frag): lane ln = q, rows quad*4+r = keys
//   == A-operand layout of mfma_16x16x16 => exp2 packs straight into PV A-frag.
// ---------------------------------------------------------------------------
__global__ __launch_bounds__(256) void attn64q(
    const bf16* __restrict__ Q, const bf16* __restrict__ K,
    const bf16* __restrict__ V, bf16* __restrict__ O)
{
    const int S = 2048, D = 1024;
    __shared__ bf16 Kl[128 * 64];       // 16 KB [key][d], swizzled
    __shared__ bf16 Vl[64 * 128];       // 16 KB [d][key], swizzled

    const int t = threadIdx.x, lane = t & 63, wave = t >> 6;
    const int ln = lane & 15, quad = lane >> 4;
    const int qt = blockIdx.x, h = blockIdx.y, b = blockIdx.z;
    const size_t kqbase = (size_t)b * S * D + (size_t)h * 64;
    const size_t vbase = ((size_t)(b * 16 + h)) * 64 * 2048;

    // Q B-fragments: wave's 16 queries (Q pre-scaled by QSCALE)
    const bf16* qp = Q + kqbase + (size_t)(qt * 64 + wave * 16 + ln) * D;
    short8 aq0 = *(const short8*)(qp + quad * 8);
    short8 aq1 = *(const short8*)(qp + 32 + quad * 8);

    f32x4 o[4];
    f32x4 l4 = (f32x4){0.f, 0.f, 0.f, 0.f};   // 4 independent denom chains
#pragma unroll
    for (int i = 0; i < 4; i++) o[i] = (f32x4){0.f, 0.f, 0.f, 0.f};

    // hoisted LDS element offsets
    const int lk = ln & 7;
    const int kof0 = ln * 64 + ((quad ^ lk) * 8);          // K-frag d 0..31
    const int kof1 = ln * 64 + (((4 | quad) ^ lk) * 8);    // K-frag d 32..63
    int vof[8];  // V b64 frag: keys nk*16 + quad*4 .. +3 at row d=ln
#pragma unroll
    for (int nk = 0; nk < 8; nk++)
        vof[nk] = ln * 128 + (((nk * 2 + (quad >> 1)) ^ lk) * 8 + (quad & 1) * 4);

    // staging indices
    const int krow = t >> 3, kidx = t & 7;        // K: 8 chunks/row
    const int vrow = t >> 4, vidx = t & 15;       // V: 16 chunks/row

    for (int kt = 0; kt < S / 128; kt++) {
#pragma unroll
        for (int p = 0; p < 4; p++) {
            int row = p * 32 + krow, idx = kidx ^ (row & 7);
            async_copy16(K + kqbase + (size_t)(kt * 128 + row) * D + idx * 8,
                         &Kl[(p * 256 + wave * 64) * 8]);
        }
#pragma unroll
        for (int p = 0; p < 4; p++) {
            int row = p * 16 + vrow, idx = vidx ^ (row & 7);
            async_copy16(V + vbase + (size_t)row * 2048 + kt * 128 + idx * 8,
                         &Vl[(p * 256 + wave * 64) * 8]);
        }
        __syncthreads();

#pragma unroll
        for (int nk = 0; nk < 8; nk++) {
            short8 kf0 = *(const short8*)&Kl[nk * 1024 + kof0];
            short8 kf1 = *(const short8*)&Kl[nk * 1024 + kof1];
            f32x4 a = (f32x4){0.f, 0.f, 0.f, 0.f};
            a = MFMA_BF16(kf0, aq0, a);   // S^T: lane ln = q, rows = keys
            a = MFMA_BF16(kf1, aq1, a);
            union { bs4 s4; bf16 hh[4]; } pk;
#pragma unroll
            for (int r = 0; r < 4; r++) {
                float p = __builtin_amdgcn_exp2f(a[r]);
                l4[r] += p;
                pk.hh[r] = (bf16)p;
            }
            // PV: 16x16x16, A = P-frag (registers), B = V b64 frag
#pragma unroll
            for (int nd = 0; nd < 4; nd++) {
                bs4 vb = *(const bs4*)&Vl[nd * 2048 + vof[nk]];
                o[nd] = MFMA16_BF16(pk.s4, vb, o[nd]);
            }
        }
        __syncthreads();
    }

    // ---- denominator: per-lane partial (q=ln, quad's key subset) ->
    // reduce across quads, redistribute to output rows q = quad*4+r ----
    float lv = l4[0] + l4[1] + l4[2] + l4[3];
    lv += __shfl_xor(lv, 16);
    lv += __shfl_xor(lv, 32);
#pragma unroll
    for (int r = 0; r < 4; r++) {
        float inv = __builtin_amdgcn_rcpf(__shfl(lv, quad * 4 + r));
        int row = qt * 64 + wave * 16 + quad * 4 + r;
#pragma unroll
        for (int nd = 0; nd < 4; nd++)
            O[((size_t)b * S + row) * D + h * 64 + nd * 16 + ln] =
                (bf16)(o[nd][r] * inv);
    }
}

// ---------------------------------------------------------------------------
extern "C" void kernel_launch(void* const* d_in, const int* in_sizes, int n_in,
                              void* d_out, int out_size, void* d_ws, size_t ws_size,
                              hipStream_t stream) {
    (void)in_sizes; (void)n_in; (void)out_size; (void)ws_size;
    const float* q  = (const float*)d_in[0];
    const float* k  = (const float*)d_in[1];
    const float* v  = (const float*)d_in[2];
    const float* Wq = (const float*)d_in[3];
    const float* bq = (const float*)d_in[4];
    const float* Wk = (const float*)d_in[5];
    const float* bk = (const float*)d_in[6];
    const float* Wv = (const float*)d_in[7];
    const float* bv = (const float*)d_in[8];
    const float* Wo = (const float*)d_in[9];
    const float* bo = (const float*)d_in[10];
    float* out = (float*)d_out;

    const int M = 4096, N = 1024;
    const size_t MN = (size_t)M * N;      // 4M elems
    const size_t NN = (size_t)N * N;      // 1M elems
    bf16* qb  = (bf16*)d_ws;
    bf16* kb  = qb + MN;
    bf16* vb  = kb + MN;
    bf16* wqb = vb + MN;
    bf16* wkb = wqb + NN;
    bf16* wvb = wkb + NN;
    bf16* wob = wvb + NN;
    bf16* Qp  = wob + NN;
    bf16* Kp  = Qp + MN;
    bf16* Vt  = Kp + MN;                  // [b][h][64][2048]
    bf16* AO  = qb;                       // qb dead after QKV projection

    dim3 blk(256);
    convert_all<<<4096, blk, 0, stream>>>(q, k, v, Wq, Wk, Wv, Wo,
                                          qb, kb, vb, wqb, wkb, wvb, wob);

    gemm_qkv<<<dim3(24, 32), blk, 0, stream>>>(qb, kb, vb, wqb, wkb, wvb,
                                               bq, bk, bv, Qp, Kp, Vt);

    attn64q<<<dim3(32, 16, 2), blk, 0, stream>>>(Qp, Kp, Vt, AO);

    gemm_fin<<<dim3(16, 32), blk, 0, stream>>>(AO, wob, bo, out);
}

// Round 9
// 225.323 us; speedup vs baseline: 1.0920x; 1.0920x over previous
//
#include <hip/hip_runtime.h>
#include <hip/hip_bf16.h>

typedef __hip_bfloat16 bf16;
typedef short short8 __attribute__((ext_vector_type(8)));
typedef short bs4 __attribute__((ext_vector_type(4)));   // NOT short4 (HIP owns that name)
typedef float f32x4 __attribute__((ext_vector_type(4)));

#define MFMA_BF16(a, b, c) __builtin_amdgcn_mfma_f32_16x16x32_bf16(a, b, c, 0, 0, 0)
#define MFMA16_BF16(a, b, c) __builtin_amdgcn_mfma_f32_16x16x16bf16_1k(a, b, c, 0, 0, 0)

// log2(e)/sqrt(1024): folded into Q-projection so attn exp is raw v_exp_f32
#define QSCALE 0.045084439f

// async global->LDS 16B: LDS dest is wave-uniform base; HW scatters lane i to +16B*i
__device__ __forceinline__ void async_copy16(const bf16* g, bf16* l) {
    __builtin_amdgcn_global_load_lds(
        (const __attribute__((address_space(1))) unsigned int*)(const void*)g,
        (__attribute__((address_space(3))) unsigned int*)(void*)l, 16, 0, 0);
}

// ---------------------------------------------------------------------------
// f32 -> bf16 pre-convert: q,k,v (4M elems each), Wq,Wk,Wv,Wo (1M each).
// ---------------------------------------------------------------------------
__global__ __launch_bounds__(256) void convert_all(
    const float* __restrict__ q, const float* __restrict__ k, const float* __restrict__ v,
    const float* __restrict__ wq, const float* __restrict__ wk,
    const float* __restrict__ wv, const float* __restrict__ wo,
    bf16* __restrict__ qb, bf16* __restrict__ kb, bf16* __restrict__ vb,
    bf16* __restrict__ wqb, bf16* __restrict__ wkb, bf16* __restrict__ wvb,
    bf16* __restrict__ wob)
{
    int blk = blockIdx.x;
    const float* s; bf16* d; int rel;
    if      (blk < 1024) { s = q;  d = qb;  rel = blk; }
    else if (blk < 2048) { s = k;  d = kb;  rel = blk - 1024; }
    else if (blk < 3072) { s = v;  d = vb;  rel = blk - 2048; }
    else if (blk < 3328) { s = wq; d = wqb; rel = blk - 3072; }
    else if (blk < 3584) { s = wk; d = wkb; rel = blk - 3328; }
    else if (blk < 3840) { s = wv; d = wvb; rel = blk - 3584; }
    else                 { s = wo; d = wob; rel = blk - 3840; }
    size_t base = (size_t)rel * 1024 + threadIdx.x;  // float4 index
#pragma unroll
    for (int i = 0; i < 4; i++) {
        float4 f = ((const float4*)s)[base + i * 256];
        union { bf16 h[4]; uint2 u; } pk;
        pk.h[0] = (bf16)f.x; pk.h[1] = (bf16)f.y;
        pk.h[2] = (bf16)f.z; pk.h[3] = (bf16)f.w;
        ((uint2*)d)[base + i * 256] = pk.u;
    }
}

// ---------------------------------------------------------------------------
// Fused QKV projection: grid (x = m-block [32], y = n-block + 8*sel [24]).
// XCD swizzle: blocks sharing the A-row-tile (fixed x, all y) have
// id = x + 32*y -> id%8 == x%8 -> same XCD -> A fetched once per XCD.
// 128x128 tile, BK=64, global_load_lds staging, XOR chunk swizzle.
// sel 0: Q (scaled by QSCALE); sel 1: K; sel 2: V transposed [b][h][64][2048].
// ---------------------------------------------------------------------------
__global__ __launch_bounds__(256) void gemm_qkv(
    const bf16* __restrict__ qb, const bf16* __restrict__ kb, const bf16* __restrict__ vb,
    const bf16* __restrict__ wqb, const bf16* __restrict__ wkb, const bf16* __restrict__ wvb,
    const float* __restrict__ bq, const float* __restrict__ bk, const float* __restrict__ bv,
    bf16* __restrict__ Qp, bf16* __restrict__ Kp, bf16* __restrict__ Vt)
{
    __shared__ bf16 Al[128 * 64];   // 16 KB
    __shared__ bf16 Bl[128 * 64];   // 16 KB

    const int sel = blockIdx.y >> 3;
    const bf16* A; const bf16* W; const float* bias;
    if      (sel == 0) { A = qb; W = wqb; bias = bq; }
    else if (sel == 1) { A = kb; W = wkb; bias = bk; }
    else               { A = vb; W = wvb; bias = bv; }

    const int K = 1024, N = 1024;
    const int t = threadIdx.x;
    const int lane = t & 63, wave = t >> 6;
    const int ln = lane & 15, quad = lane >> 4;
    const int wm = wave >> 1, wn = wave & 1;
    const int m0 = blockIdx.x * 128, n0 = (blockIdx.y & 7) * 128;

    f32x4 acc[4][4];
#pragma unroll
    for (int i = 0; i < 4; i++)
#pragma unroll
        for (int j = 0; j < 4; j++) acc[i][j] = (f32x4){0.f, 0.f, 0.f, 0.f};

    const int lk = ln & 7;
    const int srow = t >> 3, sidx0 = t & 7;

    for (int k0 = 0; k0 < K; k0 += 64) {
        const bf16* Ab = A + (size_t)m0 * K + k0;
        const bf16* Wb = W + (size_t)n0 * K + k0;
#pragma unroll
        for (int p = 0; p < 4; p++) {
            int row = p * 32 + srow, idx = sidx0 ^ (row & 7);
            async_copy16(Ab + (size_t)row * K + idx * 8, &Al[(p * 256 + wave * 64) * 8]);
        }
#pragma unroll
        for (int p = 0; p < 4; p++) {
            int row = p * 32 + srow, idx = sidx0 ^ (row & 7);
            async_copy16(Wb + (size_t)row * K + idx * 8, &Bl[(p * 256 + wave * 64) * 8]);
        }
        __syncthreads();

#pragma unroll
        for (int kk = 0; kk < 2; kk++) {
            short8 af[4], bfr[4];
#pragma unroll
            for (int i = 0; i < 4; i++) {
                int r = wm * 64 + i * 16 + ln;
                af[i] = *(const short8*)&Al[r * 64 + (((kk << 2) | quad) ^ lk) * 8];
            }
#pragma unroll
            for (int j = 0; j < 4; j++) {
                int r = wn * 64 + j * 16 + ln;
                bfr[j] = *(const short8*)&Bl[r * 64 + (((kk << 2) | quad) ^ lk) * 8];
            }
#pragma unroll
            for (int i = 0; i < 4; i++)
#pragma unroll
                for (int j = 0; j < 4; j++)
                    acc[i][j] = MFMA_BF16(af[i], bfr[j], acc[i][j]);
        }
        __syncthreads();
    }

    // epilogue: col(n) = ln, row(m) = quad*4 + r
#pragma unroll
    for (int j = 0; j < 4; j++) {
        int c = n0 + wn * 64 + j * 16 + ln;
        float bv2 = bias[c];
        if (sel == 2) {
            int h = c >> 6, dd = c & 63;
#pragma unroll
            for (int i = 0; i < 4; i++) {
                int m = m0 + wm * 64 + i * 16 + quad * 4;
                int bb = m >> 11, s = m & 2047;
                union { bf16 h4[4]; uint2 u; } pk;
#pragma unroll
                for (int r = 0; r < 4; r++) pk.h4[r] = (bf16)(acc[i][j][r] + bv2);
                *(uint2*)&Vt[(((size_t)(bb * 16 + h)) * 64 + dd) * 2048 + s] = pk.u;
            }
        } else {
            bf16* out = (sel == 0) ? Qp : Kp;
            float scl = (sel == 0) ? QSCALE : 1.0f;
#pragma unroll
            for (int i = 0; i < 4; i++) {
                int rb = m0 + wm * 64 + i * 16 + quad * 4;
#pragma unroll
                for (int r = 0; r < 4; r++)
                    out[(size_t)(rb + r) * N + c] = (bf16)((acc[i][j][r] + bv2) * scl);
            }
        }
    }
}

// ---------------------------------------------------------------------------
// Final GEMM: out = AO * Wo^T + bo, f32 output. 128(M)x64(N) tile, BK=64.
// Grid (x = m [32], y = n [16]): same-A-tile blocks -> same XCD.
// ---------------------------------------------------------------------------
__global__ __launch_bounds__(256) void gemm_fin(
    const bf16* __restrict__ A, const bf16* __restrict__ W,
    const float* __restrict__ bias, float* __restrict__ C)
{
    __shared__ bf16 Al[128 * 64];   // 16 KB
    __shared__ bf16 Bl[64 * 64];    // 8 KB

    const int K = 1024, N = 1024;
    const int t = threadIdx.x;
    const int lane = t & 63, wave = t >> 6;
    const int ln = lane & 15, quad = lane >> 4;
    const int wm = wave >> 1, wn = wave & 1;
    const int m0 = blockIdx.x * 128, n0 = blockIdx.y * 64;

    f32x4 acc[4][2];
#pragma unroll
    for (int i = 0; i < 4; i++)
#pragma unroll
        for (int j = 0; j < 2; j++) acc[i][j] = (f32x4){0.f, 0.f, 0.f, 0.f};

    const int lk = ln & 7;
    const int srow = t >> 3, sidx0 = t & 7;

    for (int k0 = 0; k0 < K; k0 += 64) {
        const bf16* Ab = A + (size_t)m0 * K + k0;
        const bf16* Wb = W + (size_t)n0 * K + k0;
#pragma unroll
        for (int p = 0; p < 4; p++) {
            int row = p * 32 + srow, idx = sidx0 ^ (row & 7);
            async_copy16(Ab + (size_t)row * K + idx * 8, &Al[(p * 256 + wave * 64) * 8]);
        }
#pragma unroll
        for (int p = 0; p < 2; p++) {
            int row = p * 32 + srow, idx = sidx0 ^ (row & 7);
            async_copy16(Wb + (size_t)row * K + idx * 8, &Bl[(p * 256 + wave * 64) * 8]);
        }
        __syncthreads();

#pragma unroll
        for (int kk = 0; kk < 2; kk++) {
            short8 af[4], bfr[2];
#pragma unroll
            for (int i = 0; i < 4; i++) {
                int r = wm * 64 + i * 16 + ln;
                af[i] = *(const short8*)&Al[r * 64 + (((kk << 2) | quad) ^ lk) * 8];
            }
#pragma unroll
            for (int j = 0; j < 2; j++) {
                int r = wn * 32 + j * 16 + ln;
                bfr[j] = *(const short8*)&Bl[r * 64 + (((kk << 2) | quad) ^ lk) * 8];
            }
#pragma unroll
            for (int i = 0; i < 4; i++)
#pragma unroll
                for (int j = 0; j < 2; j++)
                    acc[i][j] = MFMA_BF16(af[i], bfr[j], acc[i][j]);
        }
        __syncthreads();
    }

#pragma unroll
    for (int j = 0; j < 2; j++) {
        int c = n0 + wn * 32 + j * 16 + ln;
        float bv2 = bias[c];
#pragma unroll
        for (int i = 0; i < 4; i++) {
            int rb = m0 + wm * 64 + i * 16 + quad * 4;
#pragma unroll
            for (int r = 0; r < 4; r++)
                C[(size_t)(rb + r) * N + c] = acc[i][j][r] + bv2;
        }
    }
}

// ---------------------------------------------------------------------------
// Flash attention, transposed-score formulation (round-7 body), with XCD
// swizzle: grid (x = h + 16*b [32], y = qt [16]). Blocks sharing (b,h)'s
// K/V have id%8 == x%8 -> same XCD -> K/V fetched once per XCD, not 8x.
// ---------------------------------------------------------------------------
__global__ __launch_bounds__(256) void attn128q(
    const bf16* __restrict__ Q, const bf16* __restrict__ K,
    const bf16* __restrict__ V, bf16* __restrict__ O)
{
    const int S = 2048, D = 1024;
    __shared__ bf16 Kl[128 * 64];       // 16 KB [key][d], swizzled
    __shared__ bf16 Vl[64 * 128];       // 16 KB [d][key], swizzled

    const int t = threadIdx.x, lane = t & 63, wave = t >> 6;
    const int ln = lane & 15, quad = lane >> 4;
    const int h = blockIdx.x & 15, b = blockIdx.x >> 4, qt = blockIdx.y;
    const size_t kqbase = (size_t)b * S * D + (size_t)h * 64;
    const size_t vbase = ((size_t)(b * 16 + h)) * 64 * 2048;

    // Q B-fragments: 2 groups x 16 queries (Q pre-scaled by QSCALE)
    short8 aq[2][2];
#pragma unroll
    for (int g = 0; g < 2; g++) {
        const bf16* qp = Q + kqbase + (size_t)(qt * 128 + g * 64 + wave * 16 + ln) * D;
        aq[g][0] = *(const short8*)(qp + quad * 8);
        aq[g][1] = *(const short8*)(qp + 32 + quad * 8);
    }

    f32x4 o[2][4];
    float l[2] = {0.f, 0.f};
#pragma unroll
    for (int g = 0; g < 2; g++)
#pragma unroll
        for (int i = 0; i < 4; i++) o[g][i] = (f32x4){0.f, 0.f, 0.f, 0.f};

    // hoisted LDS element offsets
    const int lk = ln & 7;
    const int kof0 = ln * 64 + ((quad ^ lk) * 8);          // K-frag d 0..31
    const int kof1 = ln * 64 + (((4 | quad) ^ lk) * 8);    // K-frag d 32..63
    int vof[8];  // V b64 frag: keys nk*16 + quad*4 .. +3 at row d=ln
#pragma unroll
    for (int nk = 0; nk < 8; nk++)
        vof[nk] = ln * 128 + (((nk * 2 + (quad >> 1)) ^ lk) * 8 + (quad & 1) * 4);

    // staging indices
    const int krow = t >> 3, kidx = t & 7;        // K: 8 chunks/row
    const int vrow = t >> 4, vidx = t & 15;       // V: 16 chunks/row

    for (int kt = 0; kt < S / 128; kt++) {
#pragma unroll
        for (int p = 0; p < 4; p++) {
            int row = p * 32 + krow, idx = kidx ^ (row & 7);
            async_copy16(K + kqbase + (size_t)(kt * 128 + row) * D + idx * 8,
                         &Kl[(p * 256 + wave * 64) * 8]);
        }
#pragma unroll
        for (int p = 0; p < 4; p++) {
            int row = p * 16 + vrow, idx = vidx ^ (row & 7);
            async_copy16(V + vbase + (size_t)row * 2048 + kt * 128 + idx * 8,
                         &Vl[(p * 256 + wave * 64) * 8]);
        }
        __syncthreads();

#pragma unroll
        for (int nk = 0; nk < 8; nk++) {
            // K A-fragments (shared across both q-groups)
            short8 kf0 = *(const short8*)&Kl[nk * 1024 + kof0];
            short8 kf1 = *(const short8*)&Kl[nk * 1024 + kof1];
            bs4 pa[2];
#pragma unroll
            for (int g = 0; g < 2; g++) {
                f32x4 a = (f32x4){0.f, 0.f, 0.f, 0.f};
                a = MFMA_BF16(kf0, aq[g][0], a);   // S^T: lane ln = q, rows = keys
                a = MFMA_BF16(kf1, aq[g][1], a);
                union { bs4 s4; bf16 hh[4]; } pk;
#pragma unroll
                for (int r = 0; r < 4; r++) {
                    float p = __builtin_amdgcn_exp2f(a[r]);
                    l[g] += p;
                    pk.hh[r] = (bf16)p;
                }
                pa[g] = pk.s4;
            }
            // PV: 16x16x16, A = P-frag (registers), B = V b64 frag
#pragma unroll
            for (int nd = 0; nd < 4; nd++) {
                bs4 vb = *(const bs4*)&Vl[nd * 2048 + vof[nk]];
                o[0][nd] = MFMA16_BF16(pa[0], vb, o[0][nd]);
                o[1][nd] = MFMA16_BF16(pa[1], vb, o[1][nd]);
            }
        }
        __syncthreads();
    }

    // ---- denominators: l[g] holds this lane's keys (quad subset) for q=ln.
    // Reduce across quads, then redistribute to output rows q = quad*4+r. ----
#pragma unroll
    for (int g = 0; g < 2; g++) {
        float lv = l[g];
        lv += __shfl_xor(lv, 16);
        lv += __shfl_xor(lv, 32);
#pragma unroll
        for (int r = 0; r < 4; r++) {
            float inv = __builtin_amdgcn_rcpf(__shfl(lv, quad * 4 + r));
            int row = qt * 128 + g * 64 + wave * 16 + quad * 4 + r;
#pragma unroll
            for (int nd = 0; nd < 4; nd++)
                O[((size_t)b * S + row) * D + h * 64 + nd * 16 + ln] =
                    (bf16)(o[g][nd][r] * inv);
        }
    }
}

// ---------------------------------------------------------------------------
extern "C" void kernel_launch(void* const* d_in, const int* in_sizes, int n_in,
                              void* d_out, int out_size, void* d_ws, size_t ws_size,
                              hipStream_t stream) {
    (void)in_sizes; (void)n_in; (void)out_size; (void)ws_size;
    const float* q  = (const float*)d_in[0];
    const float* k  = (const float*)d_in[1];
    const float* v  = (const float*)d_in[2];
    const float* Wq = (const float*)d_in[3];
    const float* bq = (const float*)d_in[4];
    const float* Wk = (const float*)d_in[5];
    const float* bk = (const float*)d_in[6];
    const float* Wv = (const float*)d_in[7];
    const float* bv = (const float*)d_in[8];
    const float* Wo = (const float*)d_in[9];
    const float* bo = (const float*)d_in[10];
    float* out = (float*)d_out;

    const int M = 4096, N = 1024;
    const size_t MN = (size_t)M * N;      // 4M elems
    const size_t NN = (size_t)N * N;      // 1M elems
    bf16* qb  = (bf16*)d_ws;
    bf16* kb  = qb + MN;
    bf16* vb  = kb + MN;
    bf16* wqb = vb + MN;
    bf16* wkb = wqb + NN;
    bf16* wvb = wkb + NN;
    bf16* wob = wvb + NN;
    bf16* Qp  = wob + NN;
    bf16* Kp  = Qp + MN;
    bf16* Vt  = Kp + MN;                  // [b][h][64][2048]
    bf16* AO  = qb;                       // qb dead after QKV projection

    dim3 blk(256);
    convert_all<<<4096, blk, 0, stream>>>(q, k, v, Wq, Wk, Wv, Wo,
                                          qb, kb, vb, wqb, wkb, wvb, wob);

    gemm_qkv<<<dim3(32, 24), blk, 0, stream>>>(qb, kb, vb, wqb, wkb, wvb,
                                               bq, bk, bv, Qp, Kp, Vt);

    attn128q<<<dim3(32, 16), blk, 0, stream>>>(Qp, Kp, Vt, AO);

    gemm_fin<<<dim3(32, 16), blk, 0, stream>>>(AO, wob, bo, out);
}